// Round 5
// baseline (168.582 us; speedup 1.0000x reference)
//
#include <hip/hip_runtime.h>

// VQ-VAE quantize: z [32,64,64,64] NCHW fp32, codebook [512,64] fp32.
// out = quantized (8388608 fp32, NCHW) ++ loss scalar. N=131072, D=64, K=512.
//
// R13: fix R12's register-allocation sabotage. R12's __launch_bounds__(256,4)
// let the backend chase 8 waves/EU -> VGPR=64 with ~8.5MB/dispatch scratch
// spill traffic (WRITE 32.8->41.4MB, FETCH +6MB, MfmaUtil DOWN). Pin the
// occupancy window with amdgpu_waves_per_eu(4,4): allocator gets the full
// 128-VGPR budget for 4 waves/SIMD, no spill incentive. Structure otherwise
// identical to R12: 64-code double-buffered LDS tiles (39.9KB -> 4 blocks/CU),
// gll16 async prefetch, one barrier per tile, POSB=128.
// Numerics bit-identical: 3-pass hi/lo bf16 MFMA rank, TAU=4e-3 gap ->
// np-bit-exact block rescan; outputs exact gathers -> absmax 0.0.

typedef __bf16 bf8 __attribute__((ext_vector_type(8)));
typedef float  f4  __attribute__((ext_vector_type(4)));
typedef unsigned short us8 __attribute__((ext_vector_type(8)));

#define Dz    64
#define HWz   4096
#define Nz    131072
#define QSIZE ((size_t)Nz * Dz)     // 8388608
#define CROW  72                    // split-cb row stride (ushorts) = 144B
#define T64_USHORT 9216             // one 64-code tile (hi 4608 + lo 4608)
#define T64_BYTES  18432
#define CB_WS_BYTES (8 * 18432)     // 147456
#define TAU   4e-3f
#define POSB  128                   // positions per block

#define MFMA(A, B, C) __builtin_amdgcn_mfma_f32_16x16x32_bf16(A, B, C, 0, 0, 0)

// wave-uniform LDS dest (base + lane*16), per-lane global src
__device__ __forceinline__ void gll16(const void* g, void* l) {
    __builtin_amdgcn_global_load_lds(
        (const __attribute__((address_space(1))) void*)g,
        (__attribute__((address_space(3))) void*)l, 16, 0, 0);
}

// ---------- prep: split codebook to bf16 hi/lo 64-code tiles + exact cn ----
__global__ __launch_bounds__(64) void vq_prep(const float* __restrict__ cb,
                                              unsigned short* __restrict__ cbws,
                                              float* __restrict__ cnws) {
    const int k = blockIdx.x * 64 + threadIdx.x;    // 0..511
    const float4* row = (const float4*)(cb + (size_t)k * 64);
    {   // numpy pairwise-8 sumsq (squares round before add)
#pragma clang fp contract(off)
        float r0, r1, r2, r3, r4, r5, r6, r7;
        {
            float4 f0 = row[0], f1 = row[1];
            r0 = f0.x * f0.x; r1 = f0.y * f0.y; r2 = f0.z * f0.z; r3 = f0.w * f0.w;
            r4 = f1.x * f1.x; r5 = f1.y * f1.y; r6 = f1.z * f1.z; r7 = f1.w * f1.w;
        }
#pragma unroll
        for (int m = 1; m < 8; ++m) {
            float4 f0 = row[2 * m], f1 = row[2 * m + 1];
            r0 = r0 + f0.x * f0.x; r1 = r1 + f0.y * f0.y;
            r2 = r2 + f0.z * f0.z; r3 = r3 + f0.w * f0.w;
            r4 = r4 + f1.x * f1.x; r5 = r5 + f1.y * f1.y;
            r6 = r6 + f1.z * f1.z; r7 = r7 + f1.w * f1.w;
        }
        cnws[k] = ((r0 + r1) + (r2 + r3)) + ((r4 + r5) + (r6 + r7));
    }
    // 64-code tile: hi at (k>>6)*9216 + (k&63)*72, lo at +4608 (ushorts).
    unsigned short* hi = cbws + (size_t)(k >> 6) * T64_USHORT + (k & 63) * CROW;
    unsigned short* lo = hi + T64_USHORT / 2;
    us8* hv = (us8*)hi;
    us8* lv = (us8*)lo;
#define SPLIT2(x, H, L, i)                                             \
    {   __bf16 h = (__bf16)(x); float rr = (x) - (float)h;             \
        H[i] = __builtin_bit_cast(unsigned short, h);                  \
        L[i] = __builtin_bit_cast(unsigned short, (__bf16)rr); }
#pragma unroll
    for (int c = 0; c < 8; ++c) {
        float4 f0 = row[2 * c], f1 = row[2 * c + 1];
        us8 h8, l8;
        SPLIT2(f0.x, h8, l8, 0) SPLIT2(f0.y, h8, l8, 1)
        SPLIT2(f0.z, h8, l8, 2) SPLIT2(f0.w, h8, l8, 3)
        SPLIT2(f1.x, h8, l8, 4) SPLIT2(f1.y, h8, l8, 5)
        SPLIT2(f1.z, h8, l8, 6) SPLIT2(f1.w, h8, l8, 7)
        hv[c] = h8;
        lv[c] = l8;
    }
#undef SPLIT2
}

// ---------- main ----------
// best/second update: order matters (second from OLD best).
#define UPDR(ACCE, B, K, S)                                            \
    {   const float vv = __builtin_fmaf(ACCE, -2.0f, cnv);             \
        S = fminf(S, fmaxf(B, vv));                                    \
        K = (vv < B) ? kcand : K;                                      \
        B = fminf(B, vv); }

#define REDR(B, K, S)                                                  \
    _Pragma("unroll")                                                  \
    for (int mm = 1; mm < 16; mm <<= 1) {                              \
        const float ob = __shfl_xor(B, mm, 64);                        \
        const int   ok = __shfl_xor(K, mm, 64);                        \
        const float os = __shfl_xor(S, mm, 64);                        \
        S = fminf(fminf(S, os), fmaxf(B, ob));                         \
        K = (ob < B) ? ok : K;                                         \
        B = fminf(B, ob); }

// per position-tile T: A-frags (hi/lo x 2 k-chunks) + best/second trackers
#define DECLT(T)                                                       \
    bf8 ah##T##0, ah##T##1, al##T##0, al##T##1;                        \
    float bd##T##0 = INF, bd##T##1 = INF, bd##T##2 = INF, bd##T##3 = INF; \
    float sd##T##0 = INF, sd##T##1 = INF, sd##T##2 = INF, sd##T##3 = INF; \
    int   bk##T##0 = 0, bk##T##1 = 0, bk##T##2 = 0, bk##T##3 = 0;

#define BUILDT(T, P)                                                   \
    _Pragma("unroll")                                                  \
    for (int j = 0; j < 8; ++j) {                                      \
        const float v0 = zq[(size_t)(q * 8 + j) * HWz + (P)];          \
        const float v1 = zq[(size_t)(32 + q * 8 + j) * HWz + (P)];     \
        const __bf16 h0 = (__bf16)v0, h1 = (__bf16)v1;                 \
        ah##T##0[j] = h0; al##T##0[j] = (__bf16)(v0 - (float)h0);      \
        ah##T##1[j] = h1; al##T##1[j] = (__bf16)(v1 - (float)h1);      \
    }

#define TILE_STEP(T)                                                   \
    {   f4 acc = {0.f, 0.f, 0.f, 0.f};                                 \
        acc = MFMA(ah##T##0, bh0, acc); acc = MFMA(ah##T##1, bh1, acc);\
        acc = MFMA(al##T##0, bh0, acc); acc = MFMA(al##T##1, bh1, acc);\
        acc = MFMA(ah##T##0, bl0, acc); acc = MFMA(ah##T##1, bl1, acc);\
        UPDR(acc[0], bd##T##0, bk##T##0, sd##T##0)                     \
        UPDR(acc[1], bd##T##1, bk##T##1, sd##T##1)                     \
        UPDR(acc[2], bd##T##2, bk##T##2, sd##T##2)                     \
        UPDR(acc[3], bd##T##3, bk##T##3, sd##T##3) }

#define REDT(T)                                                        \
    REDR(bd##T##0, bk##T##0, sd##T##0) REDR(bd##T##1, bk##T##1, sd##T##1) \
    REDR(bd##T##2, bk##T##2, sd##T##2) REDR(bd##T##3, bk##T##3, sd##T##3)

#define FLAGT(T, OFF)                                                  \
    idx_s[base + (OFF) + 0] = (sd##T##0 - bd##T##0 <= TAU) ? -1 : bk##T##0; \
    idx_s[base + (OFF) + 1] = (sd##T##1 - bd##T##1 <= TAU) ? -1 : bk##T##1; \
    idx_s[base + (OFF) + 2] = (sd##T##2 - bd##T##2 <= TAU) ? -1 : bk##T##2; \
    idx_s[base + (OFF) + 3] = (sd##T##3 - bd##T##3 <= TAU) ? -1 : bk##T##3;

__global__ __launch_bounds__(256)
__attribute__((amdgpu_waves_per_eu(4, 4)))
void vq_main(
    const float* __restrict__ z, const float* __restrict__ cb,
    const unsigned short* __restrict__ cbws, const float* __restrict__ cnws,
    float* __restrict__ out, float* __restrict__ loss_accum,
    unsigned int* __restrict__ done_counter) {
    __shared__ __attribute__((aligned(16))) unsigned short cbS[2][T64_USHORT];
    __shared__ __attribute__((aligned(16))) float cn_s[512];
    __shared__ int    idx_s[POSB];
    __shared__ float  zrow_s[64];
    __shared__ float  wredD[4];
    __shared__ int    wredK[4];
    __shared__ float  wsum[4];
    __shared__ int    nfb;
    __shared__ unsigned char fbrows[POSB];

    const int t  = threadIdx.x;
    const int w  = t >> 6;
    const int l  = t & 63;
    const int q  = l >> 4;
    const int m16 = l & 15;
    const int n0g = blockIdx.x * POSB;
    const int b   = n0g >> 12;
    const int s0  = n0g & 4095;
    const float* zB = z + (size_t)b * (Dz * HWz);

    // ---- issue tile0 + cn async into LDS (18 chunks of 1024B across waves)
    {
        const char* tsrc = (const char*)cbws;
        char* tdst = (char*)&cbS[0][0];
#pragma unroll
        for (int i = 0; i < 5; ++i) {
            const int c = w + 4 * i;
            if (c < 18) gll16(tsrc + c * 1024 + l * 16, tdst + c * 1024);
        }
        if (w < 2)
            gll16((const char*)cnws + w * 1024 + l * 16, (char*)cn_s + w * 1024);
        if (t == 0) nfb = 0;
    }

    // ---- build A fragments straight from global (overlaps tile0 staging)
    const float INF = __builtin_inff();
    DECLT(A) DECLT(B)
    {
        const int pA = 32 * w + m16;
        const float* zq = zB + s0;
        BUILDT(A, pA) BUILDT(B, pA + 16)
    }
    __syncthreads();    // vmcnt(0) drain: tile0 + cn landed

    // ---- K loop: 8 tiles x 64 codes, double-buffered w/ async prefetch.
    for (int kt = 0; kt < 8; ++kt) {
        const unsigned short* cbuf = &cbS[kt & 1][0];
        if (kt < 7) {   // issue next tile BEFORE compute; lands by next barrier
            const char* tsrc = (const char*)(cbws + (size_t)(kt + 1) * T64_USHORT);
            char* tdst = (char*)&cbS[(kt + 1) & 1][0];
#pragma unroll
            for (int i = 0; i < 5; ++i) {
                const int c = w + 4 * i;
                if (c < 18) gll16(tsrc + c * 1024 + l * 16, tdst + c * 1024);
            }
        }
        const int k0 = kt * 64;
#pragma unroll
        for (int n0 = 0; n0 < 64; n0 += 16) {
            const int nlane = n0 + m16;
            const int hoff = nlane * CROW + q * 8;          // ushorts
            const bf8 bh0 = *(const bf8*)(cbuf + hoff);
            const bf8 bh1 = *(const bf8*)(cbuf + hoff + 32);
            const bf8 bl0 = *(const bf8*)(cbuf + hoff + T64_USHORT / 2);
            const bf8 bl1 = *(const bf8*)(cbuf + hoff + T64_USHORT / 2 + 32);
            const float cnv = cn_s[k0 + nlane];
            const int kcand = k0 + nlane;
            TILE_STEP(A) TILE_STEP(B)
        }
        __syncthreads();    // all reads of cbuf done; next tile's gll drained
    }

    // ---- cross-lane reduce (16-lane groups hold one row each) + flag.
    REDT(A) REDT(B)
    if (m16 == 0) {
        const int base = 32 * w + 4 * q;
        FLAGT(A, 0) FLAGT(B, 16)
    }
    __syncthreads();

    // ---- compact flagged rows (skip scan when clean)
    if (t < POSB && idx_s[t] < 0) {
        const int s = atomicAdd(&nfb, 1);
        fbrows[s] = (unsigned char)t;
    }
    __syncthreads();
    const int nfbv = nfb;

    // ---- fallback: np-bit-exact rescan for flagged rows (rare).
    for (int fi = 0; fi < nfbv; ++fi) {
        const int row = fbrows[fi];
        if (t < 64) zrow_s[t] = zB[(size_t)t * HWz + s0 + row];
        __syncthreads();
        float zn;
        {   // np pairwise-8 znorm (broadcast LDS reads)
#pragma clang fp contract(off)
            float r0, r1, r2, r3, r4, r5, r6, r7;
            r0 = zrow_s[0]*zrow_s[0]; r1 = zrow_s[1]*zrow_s[1];
            r2 = zrow_s[2]*zrow_s[2]; r3 = zrow_s[3]*zrow_s[3];
            r4 = zrow_s[4]*zrow_s[4]; r5 = zrow_s[5]*zrow_s[5];
            r6 = zrow_s[6]*zrow_s[6]; r7 = zrow_s[7]*zrow_s[7];
#pragma unroll
            for (int m = 1; m < 8; ++m) {
                float v0 = zrow_s[8*m+0], v1 = zrow_s[8*m+1];
                float v2 = zrow_s[8*m+2], v3 = zrow_s[8*m+3];
                float v4 = zrow_s[8*m+4], v5 = zrow_s[8*m+5];
                float v6 = zrow_s[8*m+6], v7 = zrow_s[8*m+7];
                r0 = r0 + v0*v0; r1 = r1 + v1*v1; r2 = r2 + v2*v2; r3 = r3 + v3*v3;
                r4 = r4 + v4*v4; r5 = r5 + v5*v5; r6 = r6 + v6*v6; r7 = r7 + v7*v7;
            }
            zn = ((r0 + r1) + (r2 + r3)) + ((r4 + r5) + (r6 + r7));
        }
        float bd; int bk;
        {   // codes t and t+256, exact sequential-d chain (R5-validated)
            float dd[2];
#pragma unroll
            for (int h = 0; h < 2; ++h) {
                const int k = t + 256 * h;
                const float4* C = (const float4*)(cb + (size_t)k * 64);
                float a = 0.f;
#pragma unroll
                for (int i = 0; i < 16; ++i) {
                    const float4 c4 = C[i];
                    a = __builtin_fmaf(zrow_s[4*i+0], c4.x, a);
                    a = __builtin_fmaf(zrow_s[4*i+1], c4.y, a);
                    a = __builtin_fmaf(zrow_s[4*i+2], c4.z, a);
                    a = __builtin_fmaf(zrow_s[4*i+3], c4.w, a);
                }
                dd[h] = (zn - 2.0f * a) + cn_s[k];
            }
            bd = dd[0]; bk = t;
            if (dd[1] < bd) { bd = dd[1]; bk = t + 256; }
        }
#pragma unroll
        for (int mm = 1; mm < 64; mm <<= 1) {
            const float ob = __shfl_xor(bd, mm, 64);
            const int   ok = __shfl_xor(bk, mm, 64);
            if (ob < bd || (ob == bd && ok < bk)) { bd = ob; bk = ok; }
        }
        if (l == 0) { wredD[w] = bd; wredK[w] = bk; }
        __syncthreads();
        if (t == 0) {
            float fb = wredD[0]; int fk = wredK[0];
#pragma unroll
            for (int i = 1; i < 4; ++i) {
                if (wredD[i] < fb || (wredD[i] == fb && wredK[i] < fk)) {
                    fb = wredD[i]; fk = wredK[i];
                }
            }
            idx_s[row] = fk;
        }
        __syncthreads();
    }

    // ---- epilogue: gather code, write q_st (NCHW coalesced), loss.
    // 2 threads per position, 32 d's each. y re-read from global (L3-warm),
    // bitwise same values as z.
    const int p  = t & 127;
    const int d0 = (t >> 7) * 32;
    const int myidx = idx_s[p];
    const float* qrow = cb + (size_t)myidx * 64 + d0;
    const float* zc = zB + s0 + p;
    float* oB = out + (size_t)b * (Dz * HWz) + s0 + p;
    float lsum = 0.f;
#pragma unroll
    for (int j = 0; j < 8; ++j) {
        const int d = d0 + 4 * j;
        const float4 q4 = *(const float4*)(qrow + 4 * j);
        const float y0 = zc[(size_t)(d + 0) * HWz];
        const float y1 = zc[(size_t)(d + 1) * HWz];
        const float y2 = zc[(size_t)(d + 2) * HWz];
        const float y3 = zc[(size_t)(d + 3) * HWz];
        const float e0 = y0 - q4.x, e1 = y1 - q4.y;
        const float e2 = y2 - q4.z, e3 = y3 - q4.w;
        lsum += e0 * e0; lsum += e1 * e1; lsum += e2 * e2; lsum += e3 * e3;
        oB[(size_t)(d + 0) * HWz] = y0 + (q4.x - y0);
        oB[(size_t)(d + 1) * HWz] = y1 + (q4.y - y1);
        oB[(size_t)(d + 2) * HWz] = y2 + (q4.z - y2);
        oB[(size_t)(d + 3) * HWz] = y3 + (q4.w - y3);
    }
#pragma unroll
    for (int off = 32; off > 0; off >>= 1) lsum += __shfl_down(lsum, off, 64);
    if (l == 0) wsum[w] = lsum;
    __syncthreads();
    if (t == 0) {
        float tot = (wsum[0] + wsum[1]) + (wsum[2] + wsum[3]);
        atomicAdd(loss_accum, tot);
        __threadfence();
        unsigned int ticket = atomicAdd(done_counter, 1u);
        if (ticket == gridDim.x - 1) {
            __threadfence();
            float total = atomicAdd(loss_accum, 0.0f);
            float X = total / (float)QSIZE;
            out[QSIZE] = X + 0.25f * X;
        }
    }
}

extern "C" void kernel_launch(void* const* d_in, const int* in_sizes, int n_in,
                              void* d_out, int out_size, void* d_ws, size_t ws_size,
                              hipStream_t stream) {
    const float* z  = (const float*)d_in[0];
    const float* cb = (const float*)d_in[1];
    float* out = (float*)d_out;
    unsigned short* cbws = (unsigned short*)d_ws;
    float* cnws = (float*)((char*)d_ws + CB_WS_BYTES);
    float* lossp = (float*)((char*)d_ws + CB_WS_BYTES + 2048);
    unsigned int* donep = (unsigned int*)(lossp + 1);
    hipMemsetAsync(lossp, 0, 8, stream);
    vq_prep<<<8, 64, 0, stream>>>(cb, cbws, cnws);
    vq_main<<<Nz / POSB, 256, 0, stream>>>(z, cb, cbws, cnws, out, lossp, donep);
}

// Round 6
// 157.090 us; speedup vs baseline: 1.0732x; 1.0732x over previous
//
#include <hip/hip_runtime.h>

// VQ-VAE quantize: z [32,64,64,64] NCHW fp32, codebook [512,64] fp32.
// out = quantized (8388608 fp32, NCHW) ++ loss scalar. N=131072, D=64, K=512.
//
// R14: register fix, attempt 2. R12 (__launch_bounds__(256,4)) and R13
// (waves_per_eu(4,4)) both produced VGPR=64 + ~8.8MB/dispatch scratch spill
// (WRITE 41.4MB): the backend rounds occupancy UP to 8 waves/EU and spills.
// R10 proved __launch_bounds__(256,2) -> VGPR=116, no spill. So: R12's
// structure (64-code double-buffered LDS tiles, 39.9KB -> 4 blocks/CU,
// gll16 async prefetch, 1 barrier/tile, POSB=128) with launch_bounds(256,2).
// Liveness ~95-100 VGPR lands in the (64,128] bucket -> 4 waves/EU granted
// by HW, LDS cap matches -> 2x R10's TLP with a non-spilling inner loop.
// Numerics bit-identical: 3-pass hi/lo bf16 MFMA rank, TAU=4e-3 gap ->
// np-bit-exact block rescan; outputs exact gathers -> absmax 0.0.

typedef __bf16 bf8 __attribute__((ext_vector_type(8)));
typedef float  f4  __attribute__((ext_vector_type(4)));
typedef unsigned short us8 __attribute__((ext_vector_type(8)));

#define Dz    64
#define HWz   4096
#define Nz    131072
#define QSIZE ((size_t)Nz * Dz)     // 8388608
#define CROW  72                    // split-cb row stride (ushorts) = 144B
#define T64_USHORT 9216             // one 64-code tile (hi 4608 + lo 4608)
#define T64_BYTES  18432
#define CB_WS_BYTES (8 * 18432)     // 147456
#define TAU   4e-3f
#define POSB  128                   // positions per block

#define MFMA(A, B, C) __builtin_amdgcn_mfma_f32_16x16x32_bf16(A, B, C, 0, 0, 0)

// wave-uniform LDS dest (base + lane*16), per-lane global src
__device__ __forceinline__ void gll16(const void* g, void* l) {
    __builtin_amdgcn_global_load_lds(
        (const __attribute__((address_space(1))) void*)g,
        (__attribute__((address_space(3))) void*)l, 16, 0, 0);
}

// ---------- prep: split codebook to bf16 hi/lo 64-code tiles + exact cn ----
__global__ __launch_bounds__(64) void vq_prep(const float* __restrict__ cb,
                                              unsigned short* __restrict__ cbws,
                                              float* __restrict__ cnws) {
    const int k = blockIdx.x * 64 + threadIdx.x;    // 0..511
    const float4* row = (const float4*)(cb + (size_t)k * 64);
    {   // numpy pairwise-8 sumsq (squares round before add)
#pragma clang fp contract(off)
        float r0, r1, r2, r3, r4, r5, r6, r7;
        {
            float4 f0 = row[0], f1 = row[1];
            r0 = f0.x * f0.x; r1 = f0.y * f0.y; r2 = f0.z * f0.z; r3 = f0.w * f0.w;
            r4 = f1.x * f1.x; r5 = f1.y * f1.y; r6 = f1.z * f1.z; r7 = f1.w * f1.w;
        }
#pragma unroll
        for (int m = 1; m < 8; ++m) {
            float4 f0 = row[2 * m], f1 = row[2 * m + 1];
            r0 = r0 + f0.x * f0.x; r1 = r1 + f0.y * f0.y;
            r2 = r2 + f0.z * f0.z; r3 = r3 + f0.w * f0.w;
            r4 = r4 + f1.x * f1.x; r5 = r5 + f1.y * f1.y;
            r6 = r6 + f1.z * f1.z; r7 = r7 + f1.w * f1.w;
        }
        cnws[k] = ((r0 + r1) + (r2 + r3)) + ((r4 + r5) + (r6 + r7));
    }
    // 64-code tile: hi at (k>>6)*9216 + (k&63)*72, lo at +4608 (ushorts).
    unsigned short* hi = cbws + (size_t)(k >> 6) * T64_USHORT + (k & 63) * CROW;
    unsigned short* lo = hi + T64_USHORT / 2;
    us8* hv = (us8*)hi;
    us8* lv = (us8*)lo;
#define SPLIT2(x, H, L, i)                                             \
    {   __bf16 h = (__bf16)(x); float rr = (x) - (float)h;             \
        H[i] = __builtin_bit_cast(unsigned short, h);                  \
        L[i] = __builtin_bit_cast(unsigned short, (__bf16)rr); }
#pragma unroll
    for (int c = 0; c < 8; ++c) {
        float4 f0 = row[2 * c], f1 = row[2 * c + 1];
        us8 h8, l8;
        SPLIT2(f0.x, h8, l8, 0) SPLIT2(f0.y, h8, l8, 1)
        SPLIT2(f0.z, h8, l8, 2) SPLIT2(f0.w, h8, l8, 3)
        SPLIT2(f1.x, h8, l8, 4) SPLIT2(f1.y, h8, l8, 5)
        SPLIT2(f1.z, h8, l8, 6) SPLIT2(f1.w, h8, l8, 7)
        hv[c] = h8;
        lv[c] = l8;
    }
#undef SPLIT2
}

// ---------- main ----------
// best/second update: order matters (second from OLD best).
#define UPDR(ACCE, B, K, S)                                            \
    {   const float vv = __builtin_fmaf(ACCE, -2.0f, cnv);             \
        S = fminf(S, fmaxf(B, vv));                                    \
        K = (vv < B) ? kcand : K;                                      \
        B = fminf(B, vv); }

#define REDR(B, K, S)                                                  \
    _Pragma("unroll")                                                  \
    for (int mm = 1; mm < 16; mm <<= 1) {                              \
        const float ob = __shfl_xor(B, mm, 64);                        \
        const int   ok = __shfl_xor(K, mm, 64);                        \
        const float os = __shfl_xor(S, mm, 64);                        \
        S = fminf(fminf(S, os), fmaxf(B, ob));                         \
        K = (ob < B) ? ok : K;                                         \
        B = fminf(B, ob); }

// per position-tile T: A-frags (hi/lo x 2 k-chunks) + best/second trackers
#define DECLT(T)                                                       \
    bf8 ah##T##0, ah##T##1, al##T##0, al##T##1;                        \
    float bd##T##0 = INF, bd##T##1 = INF, bd##T##2 = INF, bd##T##3 = INF; \
    float sd##T##0 = INF, sd##T##1 = INF, sd##T##2 = INF, sd##T##3 = INF; \
    int   bk##T##0 = 0, bk##T##1 = 0, bk##T##2 = 0, bk##T##3 = 0;

#define BUILDT(T, P)                                                   \
    _Pragma("unroll")                                                  \
    for (int j = 0; j < 8; ++j) {                                      \
        const float v0 = zq[(size_t)(q * 8 + j) * HWz + (P)];          \
        const float v1 = zq[(size_t)(32 + q * 8 + j) * HWz + (P)];     \
        const __bf16 h0 = (__bf16)v0, h1 = (__bf16)v1;                 \
        ah##T##0[j] = h0; al##T##0[j] = (__bf16)(v0 - (float)h0);      \
        ah##T##1[j] = h1; al##T##1[j] = (__bf16)(v1 - (float)h1);      \
    }

#define TILE_STEP(T)                                                   \
    {   f4 acc = {0.f, 0.f, 0.f, 0.f};                                 \
        acc = MFMA(ah##T##0, bh0, acc); acc = MFMA(ah##T##1, bh1, acc);\
        acc = MFMA(al##T##0, bh0, acc); acc = MFMA(al##T##1, bh1, acc);\
        acc = MFMA(ah##T##0, bl0, acc); acc = MFMA(ah##T##1, bl1, acc);\
        UPDR(acc[0], bd##T##0, bk##T##0, sd##T##0)                     \
        UPDR(acc[1], bd##T##1, bk##T##1, sd##T##1)                     \
        UPDR(acc[2], bd##T##2, bk##T##2, sd##T##2)                     \
        UPDR(acc[3], bd##T##3, bk##T##3, sd##T##3) }

#define REDT(T)                                                        \
    REDR(bd##T##0, bk##T##0, sd##T##0) REDR(bd##T##1, bk##T##1, sd##T##1) \
    REDR(bd##T##2, bk##T##2, sd##T##2) REDR(bd##T##3, bk##T##3, sd##T##3)

#define FLAGT(T, OFF)                                                  \
    idx_s[base + (OFF) + 0] = (sd##T##0 - bd##T##0 <= TAU) ? -1 : bk##T##0; \
    idx_s[base + (OFF) + 1] = (sd##T##1 - bd##T##1 <= TAU) ? -1 : bk##T##1; \
    idx_s[base + (OFF) + 2] = (sd##T##2 - bd##T##2 <= TAU) ? -1 : bk##T##2; \
    idx_s[base + (OFF) + 3] = (sd##T##3 - bd##T##3 <= TAU) ? -1 : bk##T##3;

__global__ __launch_bounds__(256, 2) void vq_main(
    const float* __restrict__ z, const float* __restrict__ cb,
    const unsigned short* __restrict__ cbws, const float* __restrict__ cnws,
    float* __restrict__ out, float* __restrict__ loss_accum,
    unsigned int* __restrict__ done_counter) {
    __shared__ __attribute__((aligned(16))) unsigned short cbS[2][T64_USHORT];
    __shared__ __attribute__((aligned(16))) float cn_s[512];
    __shared__ int    idx_s[POSB];
    __shared__ float  zrow_s[64];
    __shared__ float  wredD[4];
    __shared__ int    wredK[4];
    __shared__ float  wsum[4];
    __shared__ int    nfb;
    __shared__ unsigned char fbrows[POSB];

    const int t  = threadIdx.x;
    const int w  = t >> 6;
    const int l  = t & 63;
    const int q  = l >> 4;
    const int m16 = l & 15;
    const int n0g = blockIdx.x * POSB;
    const int b   = n0g >> 12;
    const int s0  = n0g & 4095;
    const float* zB = z + (size_t)b * (Dz * HWz);

    // ---- issue tile0 + cn async into LDS (18 chunks of 1024B across waves)
    {
        const char* tsrc = (const char*)cbws;
        char* tdst = (char*)&cbS[0][0];
#pragma unroll
        for (int i = 0; i < 5; ++i) {
            const int c = w + 4 * i;
            if (c < 18) gll16(tsrc + c * 1024 + l * 16, tdst + c * 1024);
        }
        if (w < 2)
            gll16((const char*)cnws + w * 1024 + l * 16, (char*)cn_s + w * 1024);
        if (t == 0) nfb = 0;
    }

    // ---- build A fragments straight from global (overlaps tile0 staging)
    const float INF = __builtin_inff();
    DECLT(A) DECLT(B)
    {
        const int pA = 32 * w + m16;
        const float* zq = zB + s0;
        BUILDT(A, pA) BUILDT(B, pA + 16)
    }
    __syncthreads();    // vmcnt(0) drain: tile0 + cn landed

    // ---- K loop: 8 tiles x 64 codes, double-buffered w/ async prefetch.
    for (int kt = 0; kt < 8; ++kt) {
        const unsigned short* cbuf = &cbS[kt & 1][0];
        if (kt < 7) {   // issue next tile BEFORE compute; lands by next barrier
            const char* tsrc = (const char*)(cbws + (size_t)(kt + 1) * T64_USHORT);
            char* tdst = (char*)&cbS[(kt + 1) & 1][0];
#pragma unroll
            for (int i = 0; i < 5; ++i) {
                const int c = w + 4 * i;
                if (c < 18) gll16(tsrc + c * 1024 + l * 16, tdst + c * 1024);
            }
        }
        const int k0 = kt * 64;
#pragma unroll
        for (int n0 = 0; n0 < 64; n0 += 16) {
            const int nlane = n0 + m16;
            const int hoff = nlane * CROW + q * 8;          // ushorts
            const bf8 bh0 = *(const bf8*)(cbuf + hoff);
            const bf8 bh1 = *(const bf8*)(cbuf + hoff + 32);
            const bf8 bl0 = *(const bf8*)(cbuf + hoff + T64_USHORT / 2);
            const bf8 bl1 = *(const bf8*)(cbuf + hoff + T64_USHORT / 2 + 32);
            const float cnv = cn_s[k0 + nlane];
            const int kcand = k0 + nlane;
            TILE_STEP(A) TILE_STEP(B)
        }
        __syncthreads();    // all reads of cbuf done; next tile's gll drained
    }

    // ---- cross-lane reduce (16-lane groups hold one row each) + flag.
    REDT(A) REDT(B)
    if (m16 == 0) {
        const int base = 32 * w + 4 * q;
        FLAGT(A, 0) FLAGT(B, 16)
    }
    __syncthreads();

    // ---- compact flagged rows (skip scan when clean)
    if (t < POSB && idx_s[t] < 0) {
        const int s = atomicAdd(&nfb, 1);
        fbrows[s] = (unsigned char)t;
    }
    __syncthreads();
    const int nfbv = nfb;

    // ---- fallback: np-bit-exact rescan for flagged rows (rare).
    for (int fi = 0; fi < nfbv; ++fi) {
        const int row = fbrows[fi];
        if (t < 64) zrow_s[t] = zB[(size_t)t * HWz + s0 + row];
        __syncthreads();
        float zn;
        {   // np pairwise-8 znorm (broadcast LDS reads)
#pragma clang fp contract(off)
            float r0, r1, r2, r3, r4, r5, r6, r7;
            r0 = zrow_s[0]*zrow_s[0]; r1 = zrow_s[1]*zrow_s[1];
            r2 = zrow_s[2]*zrow_s[2]; r3 = zrow_s[3]*zrow_s[3];
            r4 = zrow_s[4]*zrow_s[4]; r5 = zrow_s[5]*zrow_s[5];
            r6 = zrow_s[6]*zrow_s[6]; r7 = zrow_s[7]*zrow_s[7];
#pragma unroll
            for (int m = 1; m < 8; ++m) {
                float v0 = zrow_s[8*m+0], v1 = zrow_s[8*m+1];
                float v2 = zrow_s[8*m+2], v3 = zrow_s[8*m+3];
                float v4 = zrow_s[8*m+4], v5 = zrow_s[8*m+5];
                float v6 = zrow_s[8*m+6], v7 = zrow_s[8*m+7];
                r0 = r0 + v0*v0; r1 = r1 + v1*v1; r2 = r2 + v2*v2; r3 = r3 + v3*v3;
                r4 = r4 + v4*v4; r5 = r5 + v5*v5; r6 = r6 + v6*v6; r7 = r7 + v7*v7;
            }
            zn = ((r0 + r1) + (r2 + r3)) + ((r4 + r5) + (r6 + r7));
        }
        float bd; int bk;
        {   // codes t and t+256, exact sequential-d chain (R5-validated)
            float dd[2];
#pragma unroll
            for (int h = 0; h < 2; ++h) {
                const int k = t + 256 * h;
                const float4* C = (const float4*)(cb + (size_t)k * 64);
                float a = 0.f;
#pragma unroll
                for (int i = 0; i < 16; ++i) {
                    const float4 c4 = C[i];
                    a = __builtin_fmaf(zrow_s[4*i+0], c4.x, a);
                    a = __builtin_fmaf(zrow_s[4*i+1], c4.y, a);
                    a = __builtin_fmaf(zrow_s[4*i+2], c4.z, a);
                    a = __builtin_fmaf(zrow_s[4*i+3], c4.w, a);
                }
                dd[h] = (zn - 2.0f * a) + cn_s[k];
            }
            bd = dd[0]; bk = t;
            if (dd[1] < bd) { bd = dd[1]; bk = t + 256; }
        }
#pragma unroll
        for (int mm = 1; mm < 64; mm <<= 1) {
            const float ob = __shfl_xor(bd, mm, 64);
            const int   ok = __shfl_xor(bk, mm, 64);
            if (ob < bd || (ob == bd && ok < bk)) { bd = ob; bk = ok; }
        }
        if (l == 0) { wredD[w] = bd; wredK[w] = bk; }
        __syncthreads();
        if (t == 0) {
            float fb = wredD[0]; int fk = wredK[0];
#pragma unroll
            for (int i = 1; i < 4; ++i) {
                if (wredD[i] < fb || (wredD[i] == fb && wredK[i] < fk)) {
                    fb = wredD[i]; fk = wredK[i];
                }
            }
            idx_s[row] = fk;
        }
        __syncthreads();
    }

    // ---- epilogue: gather code, write q_st (NCHW coalesced), loss.
    // 2 threads per position, 32 d's each. y re-read from global (L3-warm),
    // bitwise same values as z.
    const int p  = t & 127;
    const int d0 = (t >> 7) * 32;
    const int myidx = idx_s[p];
    const float* qrow = cb + (size_t)myidx * 64 + d0;
    const float* zc = zB + s0 + p;
    float* oB = out + (size_t)b * (Dz * HWz) + s0 + p;
    float lsum = 0.f;
#pragma unroll
    for (int j = 0; j < 8; ++j) {
        const int d = d0 + 4 * j;
        const float4 q4 = *(const float4*)(qrow + 4 * j);
        const float y0 = zc[(size_t)(d + 0) * HWz];
        const float y1 = zc[(size_t)(d + 1) * HWz];
        const float y2 = zc[(size_t)(d + 2) * HWz];
        const float y3 = zc[(size_t)(d + 3) * HWz];
        const float e0 = y0 - q4.x, e1 = y1 - q4.y;
        const float e2 = y2 - q4.z, e3 = y3 - q4.w;
        lsum += e0 * e0; lsum += e1 * e1; lsum += e2 * e2; lsum += e3 * e3;
        oB[(size_t)(d + 0) * HWz] = y0 + (q4.x - y0);
        oB[(size_t)(d + 1) * HWz] = y1 + (q4.y - y1);
        oB[(size_t)(d + 2) * HWz] = y2 + (q4.z - y2);
        oB[(size_t)(d + 3) * HWz] = y3 + (q4.w - y3);
    }
#pragma unroll
    for (int off = 32; off > 0; off >>= 1) lsum += __shfl_down(lsum, off, 64);
    if (l == 0) wsum[w] = lsum;
    __syncthreads();
    if (t == 0) {
        float tot = (wsum[0] + wsum[1]) + (wsum[2] + wsum[3]);
        atomicAdd(loss_accum, tot);
        __threadfence();
        unsigned int ticket = atomicAdd(done_counter, 1u);
        if (ticket == gridDim.x - 1) {
            __threadfence();
            float total = atomicAdd(loss_accum, 0.0f);
            float X = total / (float)QSIZE;
            out[QSIZE] = X + 0.25f * X;
        }
    }
}

extern "C" void kernel_launch(void* const* d_in, const int* in_sizes, int n_in,
                              void* d_out, int out_size, void* d_ws, size_t ws_size,
                              hipStream_t stream) {
    const float* z  = (const float*)d_in[0];
    const float* cb = (const float*)d_in[1];
    float* out = (float*)d_out;
    unsigned short* cbws = (unsigned short*)d_ws;
    float* cnws = (float*)((char*)d_ws + CB_WS_BYTES);
    float* lossp = (float*)((char*)d_ws + CB_WS_BYTES + 2048);
    unsigned int* donep = (unsigned int*)(lossp + 1);
    hipMemsetAsync(lossp, 0, 8, stream);
    vq_prep<<<8, 64, 0, stream>>>(cb, cbws, cnws);
    vq_main<<<Nz / POSB, 256, 0, stream>>>(z, cb, cbws, cnws, out, lossp, donep);
}

// Round 7
// 135.188 us; speedup vs baseline: 1.2470x; 1.1620x over previous
//
#include <hip/hip_runtime.h>

// VQ-VAE quantize: z [32,64,64,64] NCHW fp32, codebook [512,64] fp32.
// out = quantized (8388608 fp32, NCHW) ++ loss scalar. N=131072, D=64, K=512.
//
// R15: whole-codebook-in-LDS, zero-phase K-loop. Evidence from R9-R14: the
// only winning lever is per-wave amortization (4 tiles/wave, R10=70us); the
// per-tile vmcnt(0)+barrier cadence is the dominant stall (issue-model says
// ~20us wall, measured 90). The split codebook is 144KB and gfx950 allows
// >128KB/workgroup LDS (proven by 8-phase GEMM template & AITER attn).
// - Stage ALL 512 codes once (144 gll16 chunks, ONE barrier), then 32
//   K-steps of pure ds_read->MFMA->UPDR with NO barriers: the compiler can
//   pipeline the whole loop.
// - POSB=512, grid=256 = 1 block/CU exactly, 8 waves, 4 pos-tiles/wave
//   (R10's amortization). LDS (149KB) caps occupancy at 1 block/CU, so
//   launch_bounds(512,2) = 256-VGPR budget with zero spill incentive.
// - UPDR second-best update via v_med3_f32 (exact: S>=B invariant), 6->5
//   VALU ops on the post-MFMA chain.
// Numerics bit-identical: 3-pass hi/lo bf16 MFMA rank, TAU=4e-3 gap ->
// np-bit-exact one-code-per-thread rescan; outputs exact gathers -> absmax 0.

typedef __bf16 bf8 __attribute__((ext_vector_type(8)));
typedef float  f4  __attribute__((ext_vector_type(4)));
typedef unsigned short us8 __attribute__((ext_vector_type(8)));

#define Dz    64
#define HWz   4096
#define Nz    131072
#define QSIZE ((size_t)Nz * Dz)     // 8388608
#define CROW  72                    // split-cb row stride (ushorts) = 144B
#define CB_USHORT 36864             // 512 rows x 72 (hi block); lo at +36864
#define CB_WS_BYTES 147456          // hi + lo
#define TAU   4e-3f
#define POSB  512                   // positions per block
// dynamic LDS layout (bytes)
#define OFF_CB    0
#define OFF_CN    147456
#define OFF_IDX   149504
#define OFF_ZROW  151552
#define OFF_WREDD 151808
#define OFF_WREDK 151840
#define OFF_WSUM  151872
#define OFF_NFB   151904
#define OFF_FBR   151920
#define SMEM_TOTAL 152960

#define MFMA(A, B, C) __builtin_amdgcn_mfma_f32_16x16x32_bf16(A, B, C, 0, 0, 0)

// wave-uniform LDS dest (base + lane*16), per-lane global src
__device__ __forceinline__ void gll16(const void* g, void* l) {
    __builtin_amdgcn_global_load_lds(
        (const __attribute__((address_space(1))) void*)g,
        (__attribute__((address_space(3))) void*)l, 16, 0, 0);
}

// ---------- prep: split codebook to bf16 hi/lo [hi(512x72) | lo(512x72)] ----
__global__ __launch_bounds__(64) void vq_prep(const float* __restrict__ cb,
                                              unsigned short* __restrict__ cbws,
                                              float* __restrict__ cnws) {
    const int k = blockIdx.x * 64 + threadIdx.x;    // 0..511
    const float4* row = (const float4*)(cb + (size_t)k * 64);
    {   // numpy pairwise-8 sumsq (squares round before add)
#pragma clang fp contract(off)
        float r0, r1, r2, r3, r4, r5, r6, r7;
        {
            float4 f0 = row[0], f1 = row[1];
            r0 = f0.x * f0.x; r1 = f0.y * f0.y; r2 = f0.z * f0.z; r3 = f0.w * f0.w;
            r4 = f1.x * f1.x; r5 = f1.y * f1.y; r6 = f1.z * f1.z; r7 = f1.w * f1.w;
        }
#pragma unroll
        for (int m = 1; m < 8; ++m) {
            float4 f0 = row[2 * m], f1 = row[2 * m + 1];
            r0 = r0 + f0.x * f0.x; r1 = r1 + f0.y * f0.y;
            r2 = r2 + f0.z * f0.z; r3 = r3 + f0.w * f0.w;
            r4 = r4 + f1.x * f1.x; r5 = r5 + f1.y * f1.y;
            r6 = r6 + f1.z * f1.z; r7 = r7 + f1.w * f1.w;
        }
        cnws[k] = ((r0 + r1) + (r2 + r3)) + ((r4 + r5) + (r6 + r7));
    }
    unsigned short* hi = cbws + (size_t)k * CROW;
    unsigned short* lo = cbws + CB_USHORT + (size_t)k * CROW;
    us8* hv = (us8*)hi;
    us8* lv = (us8*)lo;
#define SPLIT2(x, H, L, i)                                             \
    {   __bf16 h = (__bf16)(x); float rr = (x) - (float)h;             \
        H[i] = __builtin_bit_cast(unsigned short, h);                  \
        L[i] = __builtin_bit_cast(unsigned short, (__bf16)rr); }
#pragma unroll
    for (int c = 0; c < 8; ++c) {
        float4 f0 = row[2 * c], f1 = row[2 * c + 1];
        us8 h8, l8;
        SPLIT2(f0.x, h8, l8, 0) SPLIT2(f0.y, h8, l8, 1)
        SPLIT2(f0.z, h8, l8, 2) SPLIT2(f0.w, h8, l8, 3)
        SPLIT2(f1.x, h8, l8, 4) SPLIT2(f1.y, h8, l8, 5)
        SPLIT2(f1.z, h8, l8, 6) SPLIT2(f1.w, h8, l8, 7)
        hv[c] = h8;
        lv[c] = l8;
    }
#undef SPLIT2
}

// ---------- main ----------
// best/second update: order matters (second from OLD best). med3 is exact:
// with S>=B, med3(S,B,vv) == min(max(B,vv), S).
#define UPDR(ACCE, B, K, S)                                            \
    {   const float vv = __builtin_fmaf(ACCE, -2.0f, cnv);             \
        S = __builtin_amdgcn_fmed3f(S, B, vv);                         \
        K = (vv < B) ? kcand : K;                                      \
        B = fminf(B, vv); }

#define REDR(B, K, S)                                                  \
    _Pragma("unroll")                                                  \
    for (int mm = 1; mm < 16; mm <<= 1) {                              \
        const float ob = __shfl_xor(B, mm, 64);                        \
        const int   ok = __shfl_xor(K, mm, 64);                        \
        const float os = __shfl_xor(S, mm, 64);                        \
        S = fminf(fminf(S, os), fmaxf(B, ob));                         \
        K = (ob < B) ? ok : K;                                         \
        B = fminf(B, ob); }

// per position-tile T: A-frags (hi/lo x 2 k-chunks) + best/second trackers
#define DECLT(T)                                                       \
    bf8 ah##T##0, ah##T##1, al##T##0, al##T##1;                        \
    float bd##T##0 = INF, bd##T##1 = INF, bd##T##2 = INF, bd##T##3 = INF; \
    float sd##T##0 = INF, sd##T##1 = INF, sd##T##2 = INF, sd##T##3 = INF; \
    int   bk##T##0 = 0, bk##T##1 = 0, bk##T##2 = 0, bk##T##3 = 0;

#define BUILDT(T, P)                                                   \
    _Pragma("unroll")                                                  \
    for (int j = 0; j < 8; ++j) {                                      \
        const float v0 = zq[(size_t)(q * 8 + j) * HWz + (P)];          \
        const float v1 = zq[(size_t)(32 + q * 8 + j) * HWz + (P)];     \
        const __bf16 h0 = (__bf16)v0, h1 = (__bf16)v1;                 \
        ah##T##0[j] = h0; al##T##0[j] = (__bf16)(v0 - (float)h0);      \
        ah##T##1[j] = h1; al##T##1[j] = (__bf16)(v1 - (float)h1);      \
    }

#define TILE_STEP(T)                                                   \
    {   f4 acc = {0.f, 0.f, 0.f, 0.f};                                 \
        acc = MFMA(ah##T##0, bh0, acc); acc = MFMA(ah##T##1, bh1, acc);\
        acc = MFMA(al##T##0, bh0, acc); acc = MFMA(al##T##1, bh1, acc);\
        acc = MFMA(ah##T##0, bl0, acc); acc = MFMA(ah##T##1, bl1, acc);\
        UPDR(acc[0], bd##T##0, bk##T##0, sd##T##0)                     \
        UPDR(acc[1], bd##T##1, bk##T##1, sd##T##1)                     \
        UPDR(acc[2], bd##T##2, bk##T##2, sd##T##2)                     \
        UPDR(acc[3], bd##T##3, bk##T##3, sd##T##3) }

#define REDT(T)                                                        \
    REDR(bd##T##0, bk##T##0, sd##T##0) REDR(bd##T##1, bk##T##1, sd##T##1) \
    REDR(bd##T##2, bk##T##2, sd##T##2) REDR(bd##T##3, bk##T##3, sd##T##3)

#define FLAGT(T, OFF)                                                  \
    idx_s[base + (OFF) + 0] = (sd##T##0 - bd##T##0 <= TAU) ? -1 : bk##T##0; \
    idx_s[base + (OFF) + 1] = (sd##T##1 - bd##T##1 <= TAU) ? -1 : bk##T##1; \
    idx_s[base + (OFF) + 2] = (sd##T##2 - bd##T##2 <= TAU) ? -1 : bk##T##2; \
    idx_s[base + (OFF) + 3] = (sd##T##3 - bd##T##3 <= TAU) ? -1 : bk##T##3;

__global__ __launch_bounds__(512, 2) void vq_main(
    const float* __restrict__ z, const float* __restrict__ cb,
    const unsigned short* __restrict__ cbws, const float* __restrict__ cnws,
    float* __restrict__ out, float* __restrict__ loss_accum,
    unsigned int* __restrict__ done_counter) {
    extern __shared__ __attribute__((aligned(16))) char smem[];
    unsigned short* cbL   = (unsigned short*)(smem + OFF_CB);
    float* cn_s           = (float*)(smem + OFF_CN);
    int*   idx_s          = (int*)(smem + OFF_IDX);
    float* zrow_s         = (float*)(smem + OFF_ZROW);
    float* wredD          = (float*)(smem + OFF_WREDD);
    int*   wredK          = (int*)(smem + OFF_WREDK);
    float* wsum           = (float*)(smem + OFF_WSUM);
    int*   nfb            = (int*)(smem + OFF_NFB);
    unsigned short* fbrow = (unsigned short*)(smem + OFF_FBR);

    const int t  = threadIdx.x;
    const int w  = t >> 6;      // 0..7
    const int l  = t & 63;
    const int q  = l >> 4;
    const int m16 = l & 15;
    const int n0g = blockIdx.x * POSB;
    const int b   = n0g >> 12;
    const int s0  = n0g & 4095;
    const float* zB = z + (size_t)b * (Dz * HWz);

    // ---- stage ENTIRE split codebook (144KB = 144 chunks) + cn, once.
    {
        const char* tsrc = (const char*)cbws;
        char* tdst = smem + OFF_CB;
#pragma unroll
        for (int i = 0; i < 18; ++i) {
            const int c = 18 * w + i;
            gll16(tsrc + c * 1024 + l * 16, tdst + c * 1024);
        }
        if (w < 2)
            gll16((const char*)cnws + w * 1024 + l * 16,
                  smem + OFF_CN + w * 1024);
        if (t == 0) *nfb = 0;
    }

    // ---- build A fragments straight from global (overlaps staging)
    const float INF = __builtin_inff();
    DECLT(A) DECLT(B) DECLT(C) DECLT(D)
    {
        const int pA = 64 * w + m16;
        const float* zq = zB + s0;
        BUILDT(A, pA) BUILDT(B, pA + 16) BUILDT(C, pA + 32) BUILDT(D, pA + 48)
    }
    __syncthreads();    // vmcnt(0) drain: whole codebook + cn landed. ONLY
                        // barrier before the reduce phase.

    // ---- K loop: 32 steps x 16 codes, all from LDS, ZERO barriers.
#pragma unroll 4
    for (int s = 0; s < 32; ++s) {
        const int nlane = 16 * s + m16;
        const unsigned short* p = cbL + nlane * CROW + q * 8;
        const bf8 bh0 = *(const bf8*)(p);
        const bf8 bh1 = *(const bf8*)(p + 32);
        const bf8 bl0 = *(const bf8*)(p + CB_USHORT);
        const bf8 bl1 = *(const bf8*)(p + CB_USHORT + 32);
        const float cnv = cn_s[nlane];
        const int kcand = nlane;
        TILE_STEP(A) TILE_STEP(B) TILE_STEP(C) TILE_STEP(D)
    }

    // ---- cross-lane reduce (16-lane groups hold one row each) + flag.
    REDT(A) REDT(B) REDT(C) REDT(D)
    if (m16 == 0) {
        const int base = 64 * w + 4 * q;
        FLAGT(A, 0) FLAGT(B, 16) FLAGT(C, 32) FLAGT(D, 48)
    }
    __syncthreads();

    // ---- compact flagged rows (skip scan when clean)
    if (idx_s[t] < 0) {
        const int s = atomicAdd(nfb, 1);
        fbrow[s] = (unsigned short)t;
    }
    __syncthreads();
    const int nfbv = *nfb;

    // ---- fallback: np-bit-exact rescan for flagged rows (rare).
    // One code per thread (512 threads = 512 codes), exact sequential-d chain.
    for (int fi = 0; fi < nfbv; ++fi) {
        const int row = fbrow[fi];
        if (t < 64) zrow_s[t] = zB[(size_t)t * HWz + s0 + row];
        __syncthreads();
        float zn;
        {   // np pairwise-8 znorm (broadcast LDS reads)
#pragma clang fp contract(off)
            float r0, r1, r2, r3, r4, r5, r6, r7;
            r0 = zrow_s[0]*zrow_s[0]; r1 = zrow_s[1]*zrow_s[1];
            r2 = zrow_s[2]*zrow_s[2]; r3 = zrow_s[3]*zrow_s[3];
            r4 = zrow_s[4]*zrow_s[4]; r5 = zrow_s[5]*zrow_s[5];
            r6 = zrow_s[6]*zrow_s[6]; r7 = zrow_s[7]*zrow_s[7];
#pragma unroll
            for (int m = 1; m < 8; ++m) {
                float v0 = zrow_s[8*m+0], v1 = zrow_s[8*m+1];
                float v2 = zrow_s[8*m+2], v3 = zrow_s[8*m+3];
                float v4 = zrow_s[8*m+4], v5 = zrow_s[8*m+5];
                float v6 = zrow_s[8*m+6], v7 = zrow_s[8*m+7];
                r0 = r0 + v0*v0; r1 = r1 + v1*v1; r2 = r2 + v2*v2; r3 = r3 + v3*v3;
                r4 = r4 + v4*v4; r5 = r5 + v5*v5; r6 = r6 + v6*v6; r7 = r7 + v7*v7;
            }
            zn = ((r0 + r1) + (r2 + r3)) + ((r4 + r5) + (r6 + r7));
        }
        float bd; int bk;
        {
            const float4* C = (const float4*)(cb + (size_t)t * 64);
            float a = 0.f;
#pragma unroll
            for (int i = 0; i < 16; ++i) {
                const float4 c4 = C[i];
                a = __builtin_fmaf(zrow_s[4*i+0], c4.x, a);
                a = __builtin_fmaf(zrow_s[4*i+1], c4.y, a);
                a = __builtin_fmaf(zrow_s[4*i+2], c4.z, a);
                a = __builtin_fmaf(zrow_s[4*i+3], c4.w, a);
            }
            bd = (zn - 2.0f * a) + cn_s[t];
            bk = t;
        }
#pragma unroll
        for (int mm = 1; mm < 64; mm <<= 1) {
            const float ob = __shfl_xor(bd, mm, 64);
            const int   ok = __shfl_xor(bk, mm, 64);
            if (ob < bd || (ob == bd && ok < bk)) { bd = ob; bk = ok; }
        }
        if (l == 0) { wredD[w] = bd; wredK[w] = bk; }
        __syncthreads();
        if (t == 0) {
            float fb = wredD[0]; int fk = wredK[0];
#pragma unroll
            for (int i = 1; i < 8; ++i) {
                if (wredD[i] < fb || (wredD[i] == fb && wredK[i] < fk)) {
                    fb = wredD[i]; fk = wredK[i];
                }
            }
            idx_s[row] = fk;
        }
        __syncthreads();
    }

    // ---- epilogue: gather code, write q_st (NCHW coalesced), loss.
    // One thread per position, full 64-d column. y re-read from global
    // (coalesced, L3-warm) -- bitwise same values as z.
    const int myidx = idx_s[t];
    const float* qrow = cb + (size_t)myidx * 64;
    const float* zc = zB + s0 + t;
    float* oB = out + (size_t)b * (Dz * HWz) + s0 + t;
    float lsum = 0.f;
#pragma unroll
    for (int j = 0; j < 16; ++j) {
        const int d = 4 * j;
        const float4 q4 = *(const float4*)(qrow + d);
        const float y0 = zc[(size_t)(d + 0) * HWz];
        const float y1 = zc[(size_t)(d + 1) * HWz];
        const float y2 = zc[(size_t)(d + 2) * HWz];
        const float y3 = zc[(size_t)(d + 3) * HWz];
        const float e0 = y0 - q4.x, e1 = y1 - q4.y;
        const float e2 = y2 - q4.z, e3 = y3 - q4.w;
        lsum += e0 * e0; lsum += e1 * e1; lsum += e2 * e2; lsum += e3 * e3;
        oB[(size_t)(d + 0) * HWz] = y0 + (q4.x - y0);
        oB[(size_t)(d + 1) * HWz] = y1 + (q4.y - y1);
        oB[(size_t)(d + 2) * HWz] = y2 + (q4.z - y2);
        oB[(size_t)(d + 3) * HWz] = y3 + (q4.w - y3);
    }
#pragma unroll
    for (int off = 32; off > 0; off >>= 1) lsum += __shfl_down(lsum, off, 64);
    if (l == 0) wsum[w] = lsum;
    __syncthreads();
    if (t == 0) {
        float tot = ((wsum[0] + wsum[1]) + (wsum[2] + wsum[3]))
                  + ((wsum[4] + wsum[5]) + (wsum[6] + wsum[7]));
        atomicAdd(loss_accum, tot);
        __threadfence();
        unsigned int ticket = atomicAdd(done_counter, 1u);
        if (ticket == gridDim.x - 1) {
            __threadfence();
            float total = atomicAdd(loss_accum, 0.0f);
            float X = total / (float)QSIZE;
            out[QSIZE] = X + 0.25f * X;
        }
    }
}

extern "C" void kernel_launch(void* const* d_in, const int* in_sizes, int n_in,
                              void* d_out, int out_size, void* d_ws, size_t ws_size,
                              hipStream_t stream) {
    const float* z  = (const float*)d_in[0];
    const float* cb = (const float*)d_in[1];
    float* out = (float*)d_out;
    unsigned short* cbws = (unsigned short*)d_ws;
    float* cnws = (float*)((char*)d_ws + CB_WS_BYTES);
    float* lossp = (float*)((char*)d_ws + CB_WS_BYTES + 2048);
    unsigned int* donep = (unsigned int*)(lossp + 1);
    static bool attr_done = false;
    if (!attr_done) {
        (void)hipFuncSetAttribute((const void*)vq_main,
                                  hipFuncAttributeMaxDynamicSharedMemorySize,
                                  SMEM_TOTAL);
        attr_done = true;
    }
    hipMemsetAsync(lossp, 0, 8, stream);
    vq_prep<<<8, 64, 0, stream>>>(cb, cbws, cnws);
    vq_main<<<Nz / POSB, 512, SMEM_TOTAL, stream>>>(z, cb, cbws, cnws, out,
                                                    lossp, donep);
}